// Round 1
// baseline (223.741 us; speedup 1.0000x reference)
//
#include <hip/hip_runtime.h>

#define BN 4
#define NN 8192
#define EE 128
#define HH 4
#define DD 32
#define WW 33
#define MROWS (BN*NN)            // 32768
#define QELEMS (MROWS*EE)        // 4194304
#define WELEMS (EE*EE)           // 16384

typedef __bf16 bf16x8 __attribute__((ext_vector_type(8)));
typedef float f32x4 __attribute__((ext_vector_type(4)));
typedef unsigned short u16x8 __attribute__((ext_vector_type(8)));

static __device__ __forceinline__ unsigned short f2bf(float x){
    unsigned u = __float_as_uint(x);
    u += 0x7fffu + ((u >> 16) & 1u);
    return (unsigned short)(u >> 16);
}
static __device__ __forceinline__ float bf2f(unsigned short h){
    return __uint_as_float(((unsigned)h) << 16);
}
static __device__ __forceinline__ bf16x8 ld_bf8(const unsigned short* p){
    u16x8 v = *(const u16x8*)p;
    return __builtin_bit_cast(bf16x8, v);
}

// ---------------- prep: split fp32 -> bf16 hi/lo ----------------
__global__ void __launch_bounds__(256) prep_q(const float* __restrict__ q,
        unsigned short* __restrict__ qh, unsigned short* __restrict__ ql){
    int i = blockIdx.x*256 + threadIdx.x;       // 0..1048575 (float4 index)
    float4 v = ((const float4*)q)[i];
    float vv[4] = {v.x, v.y, v.z, v.w};
    unsigned short h[4], l[4];
    #pragma unroll
    for (int j=0;j<4;j++){
        h[j] = f2bf(vv[j]);
        l[j] = f2bf(vv[j] - bf2f(h[j]));
    }
    *(ushort4*)(qh + (size_t)i*4) = make_ushort4(h[0],h[1],h[2],h[3]);
    *(ushort4*)(ql + (size_t)i*4) = make_ushort4(l[0],l[1],l[2],l[3]);
}

__global__ void __launch_bounds__(256) prep_w(const float* __restrict__ wq, const float* __restrict__ wk,
        const float* __restrict__ wv, const float* __restrict__ wo,
        unsigned short* __restrict__ wh, unsigned short* __restrict__ wl){
    int i = blockIdx.x*256 + threadIdx.x;       // 0..65535
    int sel = i >> 14;
    const float* src = (sel==0)? wq : (sel==1)? wk : (sel==2)? wv : wo;
    float x = src[i & (WELEMS-1)];
    unsigned short h = f2bf(x);
    wh[i] = h;
    wl[i] = f2bf(x - bf2f(h));
}

// ---------------- split-bf16 MFMA GEMM body (C = A @ W^T + bias) ----------------
// A: (rows x 128) as hi/lo bf16 row-major. W: (128 x 128) row-major hi/lo bf16.
// 16x16x32 bf16 MFMA. Wave computes 16 rows x 128 cols.
__device__ __forceinline__ void gemm_body(const unsigned short* __restrict__ inh,
        const unsigned short* __restrict__ inl,
        const unsigned short* __restrict__ WH, const unsigned short* __restrict__ WL,
        const float* __restrict__ bias, float* __restrict__ out, int row0)
{
    const int lane = threadIdx.x & 63;
    const int m = lane & 15, g = lane >> 4;
    bf16x8 aH[4], aL[4];
    const size_t abase = (size_t)(row0 + m) * EE;
    #pragma unroll
    for (int kc=0;kc<4;kc++){
        aH[kc] = ld_bf8(inh + abase + kc*32 + g*8);
        aL[kc] = ld_bf8(inl + abase + kc*32 + g*8);
    }
    #pragma unroll
    for (int ct=0; ct<8; ct++){
        const int col0 = ct*16;
        const size_t wbase = (size_t)(col0 + m) * EE;
        f32x4 acc = {0.f,0.f,0.f,0.f};
        #pragma unroll
        for (int kc=0;kc<4;kc++){
            bf16x8 bH = ld_bf8(WH + wbase + kc*32 + g*8);
            bf16x8 bL = ld_bf8(WL + wbase + kc*32 + g*8);
            acc = __builtin_amdgcn_mfma_f32_16x16x32_bf16(aH[kc], bH, acc, 0,0,0);
            acc = __builtin_amdgcn_mfma_f32_16x16x32_bf16(aH[kc], bL, acc, 0,0,0);
            acc = __builtin_amdgcn_mfma_f32_16x16x32_bf16(aL[kc], bH, acc, 0,0,0);
        }
        const float bv = bias[col0 + m];
        #pragma unroll
        for (int r=0;r<4;r++){
            int row = row0 + g*4 + r;          // D: col = lane&15, row = g*4 + r
            out[(size_t)row*EE + col0 + m] = acc[r] + bv;
        }
    }
}

__global__ void __launch_bounds__(256) gemm_qkv(const unsigned short* __restrict__ qh,
        const unsigned short* __restrict__ ql,
        const unsigned short* __restrict__ wh, const unsigned short* __restrict__ wl,
        const float* __restrict__ bq, const float* __restrict__ bk, const float* __restrict__ bv_,
        float* __restrict__ Qf, float* __restrict__ Kf, float* __restrict__ Vf)
{
    const int p = blockIdx.y;
    const int wid = threadIdx.x >> 6;
    const int row0 = blockIdx.x*64 + wid*16;
    const unsigned short* WH = wh + p*WELEMS;
    const unsigned short* WL = wl + p*WELEMS;
    const float* bias = (p==0)? bq : (p==1)? bk : bv_;
    float* out = (p==0)? Qf : (p==1)? Kf : Vf;
    gemm_body(qh, ql, WH, WL, bias, out, row0);
}

__global__ void __launch_bounds__(256) gemm_o(const unsigned short* __restrict__ ah,
        const unsigned short* __restrict__ al,
        const unsigned short* __restrict__ WH, const unsigned short* __restrict__ WL,
        const float* __restrict__ bo, float* __restrict__ out)
{
    const int wid = threadIdx.x >> 6;
    const int row0 = blockIdx.x*64 + wid*16;
    gemm_body(ah, al, WH, WL, bo, out, row0);
}

// ---------------- sliding-window attention, fp32 exact ----------------
// 1 thread = 1 position. Block = 128 positions of one (b,h). LDS stride 33 (bank-shift 1).
__global__ void __launch_bounds__(128) attn_kernel(const float* __restrict__ Qf,
        const float* __restrict__ Kf, const float* __restrict__ Vf,
        float* __restrict__ probs, unsigned short* __restrict__ ah, unsigned short* __restrict__ al)
{
    __shared__ float Kl[160*33];
    __shared__ float Vl[160*33];
    const int t = threadIdx.x;
    const int bh = blockIdx.y;
    const int b = bh >> 2, h = bh & 3;
    const int n0 = blockIdx.x * 128;
    const size_t rowbase = (size_t)b * NN;

    // stage K/V rows [n0-16, n0+144) slice [h*32, h*32+32), zero-fill OOB
    #pragma unroll
    for (int i=0;i<10;i++){
        int idx = t + i*128;                   // 0..1279
        int row = idx >> 3, q4 = idx & 7;
        int grow = n0 - 16 + row;
        float4 kv = make_float4(0.f,0.f,0.f,0.f);
        float4 vv = make_float4(0.f,0.f,0.f,0.f);
        if (grow >= 0 && grow < NN){
            size_t goff = (rowbase + grow)*EE + h*DD + q4*4;
            kv = *(const float4*)(Kf + goff);
            vv = *(const float4*)(Vf + goff);
        }
        int lo = row*33 + q4*4;
        Kl[lo+0]=kv.x; Kl[lo+1]=kv.y; Kl[lo+2]=kv.z; Kl[lo+3]=kv.w;
        Vl[lo+0]=vv.x; Vl[lo+1]=vv.y; Vl[lo+2]=vv.z; Vl[lo+3]=vv.w;
    }
    __syncthreads();

    const int n = n0 + t;
    float qr[32];
    {
        const float4* qp = (const float4*)(Qf + (rowbase + n)*EE + h*DD);
        #pragma unroll
        for (int i=0;i<8;i++){
            float4 v = qp[i];
            qr[i*4]=v.x; qr[i*4+1]=v.y; qr[i*4+2]=v.z; qr[i*4+3]=v.w;
        }
    }
    float sc[WW];
    #pragma unroll
    for (int w=0; w<WW; w++){
        const float* kr = &Kl[(t+w)*33];
        float s = 0.f;
        #pragma unroll
        for (int k=0;k<32;k++) s = fmaf(qr[k], kr[k], s);
        sc[w] = s * 0.17677669529663687f;      // 1/sqrt(32)
    }
    float mx = sc[0];
    #pragma unroll
    for (int w=1;w<WW;w++) mx = fmaxf(mx, sc[w]);
    float sum = 0.f;
    #pragma unroll
    for (int w=0;w<WW;w++){ sc[w] = __expf(sc[w]-mx); sum += sc[w]; }
    float inv = 1.f / sum;
    float* pp = probs + ((size_t)bh*NN + n)*WW;
    #pragma unroll
    for (int w=0;w<WW;w++){ sc[w] *= inv; pp[w] = sc[w]; }

    float acc[32];
    #pragma unroll
    for (int k=0;k<32;k++) acc[k]=0.f;
    #pragma unroll
    for (int w=0;w<WW;w++){
        const float* vr = &Vl[(t+w)*33];
        float p = sc[w];
        #pragma unroll
        for (int k=0;k<32;k++) acc[k] = fmaf(p, vr[k], acc[k]);
    }
    unsigned short hi[32], lo2[32];
    #pragma unroll
    for (int k=0;k<32;k++){ hi[k]=f2bf(acc[k]); lo2[k]=f2bf(acc[k]-bf2f(hi[k])); }
    size_t aoff = (rowbase + n)*EE + h*DD;
    #pragma unroll
    for (int k8=0;k8<8;k8++){
        *(ushort4*)(ah + aoff + k8*4) = make_ushort4(hi[k8*4],hi[k8*4+1],hi[k8*4+2],hi[k8*4+3]);
        *(ushort4*)(al + aoff + k8*4) = make_ushort4(lo2[k8*4],lo2[k8*4+1],lo2[k8*4+2],lo2[k8*4+3]);
    }
}

extern "C" void kernel_launch(void* const* d_in, const int* in_sizes, int n_in,
                              void* d_out, int out_size, void* d_ws, size_t ws_size,
                              hipStream_t stream) {
    const float* q  = (const float*)d_in[0];
    const float* Wq = (const float*)d_in[1];  const float* bq = (const float*)d_in[2];
    const float* Wk = (const float*)d_in[3];  const float* bk = (const float*)d_in[4];
    const float* Wv = (const float*)d_in[5];  const float* bv = (const float*)d_in[6];
    const float* Wo = (const float*)d_in[7];  const float* bo = (const float*)d_in[8];

    float* out   = (float*)d_out;             // (B,N,E) = 4194304 floats
    float* probs = out + QELEMS;              // (B,H,N,W) = 4325376 floats

    // workspace carve (attn hi/lo aliases dead q_hi/q_lo; peak ~64.3 MB)
    unsigned short* q_hi = (unsigned short*)d_ws;
    unsigned short* q_lo = q_hi + QELEMS;
    unsigned short* w_hi = q_lo + QELEMS;
    unsigned short* w_lo = w_hi + 4*WELEMS;
    float* Qf = (float*)(w_lo + 4*WELEMS);
    float* Kf = Qf + QELEMS;
    float* Vf = Kf + QELEMS;
    unsigned short* a_hi = q_hi;   // q_hi/q_lo dead after gemm_qkv
    unsigned short* a_lo = q_lo;

    prep_q<<<QELEMS/4/256, 256, 0, stream>>>(q, q_hi, q_lo);
    prep_w<<<4*WELEMS/256, 256, 0, stream>>>(Wq, Wk, Wv, Wo, w_hi, w_lo);
    gemm_qkv<<<dim3(MROWS/64, 3), 256, 0, stream>>>(q_hi, q_lo, w_hi, w_lo,
                                                    bq, bk, bv, Qf, Kf, Vf);
    attn_kernel<<<dim3(NN/128, BN*HH), 128, 0, stream>>>(Qf, Kf, Vf, probs, a_hi, a_lo);
    gemm_o<<<dim3(MROWS/64, 1), 256, 0, stream>>>(a_hi, a_lo,
                                                  w_hi + 3*WELEMS, w_lo + 3*WELEMS, bo, out);
}

// Round 2
// 199.034 us; speedup vs baseline: 1.1241x; 1.1241x over previous
//
#include <hip/hip_runtime.h>

#define BN 4
#define NN 8192
#define EE 128
#define HH 4
#define DD 32
#define WW 33
#define MROWS (BN*NN)            // 32768
#define QELEMS (MROWS*EE)        // 4194304
#define WELEMS (EE*EE)           // 16384

typedef __bf16 bf16x8 __attribute__((ext_vector_type(8)));
typedef float f32x4 __attribute__((ext_vector_type(4)));
typedef unsigned short u16x8 __attribute__((ext_vector_type(8)));

static __device__ __forceinline__ unsigned short f2bf(float x){
    unsigned u = __float_as_uint(x);
    u += 0x7fffu + ((u >> 16) & 1u);
    return (unsigned short)(u >> 16);
}
static __device__ __forceinline__ float bf2f(unsigned short h){
    return __uint_as_float(((unsigned)h) << 16);
}
static __device__ __forceinline__ bf16x8 ld_bf8(const unsigned short* p){
    u16x8 v = *(const u16x8*)p;
    return __builtin_bit_cast(bf16x8, v);
}

// ---------------- prep: weights fp32 -> bf16 hi/lo ----------------
__global__ void __launch_bounds__(256) prep_w(const float* __restrict__ wq, const float* __restrict__ wk,
        const float* __restrict__ wv, const float* __restrict__ wo,
        unsigned short* __restrict__ wh, unsigned short* __restrict__ wl){
    int i = blockIdx.x*256 + threadIdx.x;       // 0..65535
    int sel = i >> 14;
    const float* src = (sel==0)? wq : (sel==1)? wk : (sel==2)? wv : wo;
    float x = src[i & (WELEMS-1)];
    unsigned short h = f2bf(x);
    wh[i] = h;
    wl[i] = f2bf(x - bf2f(h));
}

// ---------------- fused QKV projection: reads q f32, splits in-reg ----------------
// Wave = 16 rows x 128 cols x 3 projections. Block = 4 waves = 64 rows.
__global__ void __launch_bounds__(256) gemm_qkv(const float* __restrict__ q,
        const unsigned short* __restrict__ wh, const unsigned short* __restrict__ wl,
        const float* __restrict__ bq, const float* __restrict__ bk, const float* __restrict__ bv_,
        float* __restrict__ Qf, float* __restrict__ Kf, float* __restrict__ Vf)
{
    const int wid = threadIdx.x >> 6;
    const int lane = threadIdx.x & 63;
    const int m = lane & 15, g = lane >> 4;
    const int row0 = blockIdx.x*64 + wid*16;

    // A fragments: row (row0+m), dims kc*32 + g*8 .. +8, split f32 -> hi/lo bf16
    bf16x8 aH[4], aL[4];
    const float* qrow = q + (size_t)(row0 + m) * EE;
    #pragma unroll
    for (int kc=0;kc<4;kc++){
        float4 v0 = *(const float4*)(qrow + kc*32 + g*8);
        float4 v1 = *(const float4*)(qrow + kc*32 + g*8 + 4);
        float vv[8] = {v0.x,v0.y,v0.z,v0.w,v1.x,v1.y,v1.z,v1.w};
        u16x8 hh, ll;
        #pragma unroll
        for (int j=0;j<8;j++){
            unsigned short h = f2bf(vv[j]);
            hh[j] = h;
            ll[j] = f2bf(vv[j] - bf2f(h));
        }
        aH[kc] = __builtin_bit_cast(bf16x8, hh);
        aL[kc] = __builtin_bit_cast(bf16x8, ll);
    }

    const float* biases[3] = {bq, bk, bv_};
    float* outs[3] = {Qf, Kf, Vf};
    #pragma unroll
    for (int p=0;p<3;p++){
        const unsigned short* WH = wh + p*WELEMS;
        const unsigned short* WL = wl + p*WELEMS;
        const float* bias = biases[p];
        float* out = outs[p];
        #pragma unroll
        for (int ct=0; ct<8; ct++){
            const int col0 = ct*16;
            const size_t wbase = (size_t)(col0 + m) * EE;
            f32x4 acc = {0.f,0.f,0.f,0.f};
            #pragma unroll
            for (int kc=0;kc<4;kc++){
                bf16x8 bH = ld_bf8(WH + wbase + kc*32 + g*8);
                bf16x8 bL = ld_bf8(WL + wbase + kc*32 + g*8);
                acc = __builtin_amdgcn_mfma_f32_16x16x32_bf16(aH[kc], bH, acc, 0,0,0);
                acc = __builtin_amdgcn_mfma_f32_16x16x32_bf16(aH[kc], bL, acc, 0,0,0);
                acc = __builtin_amdgcn_mfma_f32_16x16x32_bf16(aL[kc], bH, acc, 0,0,0);
            }
            const float bv = bias[col0 + m];
            #pragma unroll
            for (int r=0;r<4;r++){
                int row = row0 + g*4 + r;          // D: col = lane&15, row = g*4 + r
                out[(size_t)row*EE + col0 + m] = acc[r] + bv;
            }
        }
    }
}

// ---------------- output projection (A = attn out, bf16 hi/lo in ws) ----------------
__device__ __forceinline__ void gemm_body(const unsigned short* __restrict__ inh,
        const unsigned short* __restrict__ inl,
        const unsigned short* __restrict__ WH, const unsigned short* __restrict__ WL,
        const float* __restrict__ bias, float* __restrict__ out, int row0)
{
    const int lane = threadIdx.x & 63;
    const int m = lane & 15, g = lane >> 4;
    bf16x8 aH[4], aL[4];
    const size_t abase = (size_t)(row0 + m) * EE;
    #pragma unroll
    for (int kc=0;kc<4;kc++){
        aH[kc] = ld_bf8(inh + abase + kc*32 + g*8);
        aL[kc] = ld_bf8(inl + abase + kc*32 + g*8);
    }
    #pragma unroll
    for (int ct=0; ct<8; ct++){
        const int col0 = ct*16;
        const size_t wbase = (size_t)(col0 + m) * EE;
        f32x4 acc = {0.f,0.f,0.f,0.f};
        #pragma unroll
        for (int kc=0;kc<4;kc++){
            bf16x8 bH = ld_bf8(WH + wbase + kc*32 + g*8);
            bf16x8 bL = ld_bf8(WL + wbase + kc*32 + g*8);
            acc = __builtin_amdgcn_mfma_f32_16x16x32_bf16(aH[kc], bH, acc, 0,0,0);
            acc = __builtin_amdgcn_mfma_f32_16x16x32_bf16(aH[kc], bL, acc, 0,0,0);
            acc = __builtin_amdgcn_mfma_f32_16x16x32_bf16(aL[kc], bH, acc, 0,0,0);
        }
        const float bv = bias[col0 + m];
        #pragma unroll
        for (int r=0;r<4;r++){
            int row = row0 + g*4 + r;
            out[(size_t)row*EE + col0 + m] = acc[r] + bv;
        }
    }
}

__global__ void __launch_bounds__(256) gemm_o(const unsigned short* __restrict__ ah,
        const unsigned short* __restrict__ al,
        const unsigned short* __restrict__ WH, const unsigned short* __restrict__ WL,
        const float* __restrict__ bo, float* __restrict__ out)
{
    const int wid = threadIdx.x >> 6;
    const int row0 = blockIdx.x*64 + wid*16;
    gemm_body(ah, al, WH, WL, bo, out, row0);
}

// ---------------- sliding-window attention, fp32 exact ----------------
// 2 threads per position (each owns 16 of D=32). Block = 256 thr = 128 positions
// of one (b,h). LDS stride 33 (bank-shift +1 per row).
__global__ void __launch_bounds__(256,3) attn_kernel(const float* __restrict__ Qf,
        const float* __restrict__ Kf, const float* __restrict__ Vf,
        float* __restrict__ probs, unsigned short* __restrict__ ah, unsigned short* __restrict__ al)
{
    __shared__ float Kl[160*33];
    __shared__ float Vl[160*33];
    const int t = threadIdx.x;
    const int bh = blockIdx.y;
    const int b = bh >> 2, h = bh & 3;
    const int n0 = blockIdx.x * 128;
    const size_t rowbase = (size_t)b * NN;

    // stage K/V rows [n0-16, n0+144) slice [h*32, h*32+32), zero-fill OOB
    #pragma unroll
    for (int i=0;i<5;i++){
        int idx = t + i*256;                   // 0..1279
        int row = idx >> 3, q4 = idx & 7;
        int grow = n0 - 16 + row;
        float4 kv = make_float4(0.f,0.f,0.f,0.f);
        float4 vv = make_float4(0.f,0.f,0.f,0.f);
        if (grow >= 0 && grow < NN){
            size_t goff = (rowbase + grow)*EE + h*DD + q4*4;
            kv = *(const float4*)(Kf + goff);
            vv = *(const float4*)(Vf + goff);
        }
        int lo = row*33 + q4*4;
        *(float4*)(Kl + lo) = kv;
        *(float4*)(Vl + lo) = vv;
    }
    __syncthreads();

    const int p = t >> 1, e = t & 1;           // position p, half e
    const int n = n0 + p;

    float qr[16];
    {
        const float4* qp = (const float4*)(Qf + (rowbase + n)*EE + h*DD + e*16);
        #pragma unroll
        for (int i=0;i<4;i++){
            float4 v = qp[i];
            qr[i*4]=v.x; qr[i*4+1]=v.y; qr[i*4+2]=v.z; qr[i*4+3]=v.w;
        }
    }

    float sc[WW];
    #pragma unroll
    for (int w=0; w<WW; w++){
        const float* kr = &Kl[(p+w)*33 + e*16];
        float s = 0.f;
        #pragma unroll
        for (int k=0;k<16;k++) s = fmaf(qr[k], kr[k], s);
        sc[w] = s;
    }
    // pair-reduce: both threads end with identical full dot products
    #pragma unroll
    for (int w=0; w<WW; w++){
        sc[w] = (sc[w] + __shfl_xor(sc[w], 1)) * 0.17677669529663687f;  // 1/sqrt(32)
    }

    float mx = sc[0];
    #pragma unroll
    for (int w=1;w<WW;w++) mx = fmaxf(mx, sc[w]);
    float sum = 0.f;
    #pragma unroll
    for (int w=0;w<WW;w++){ sc[w] = __expf(sc[w]-mx); sum += sc[w]; }
    float inv = 1.f / sum;
    #pragma unroll
    for (int w=0;w<WW;w++) sc[w] *= inv;

    // probs: pair splits the 33 writes (e=0 -> w<17, e=1 -> w>=17)
    float* pp = probs + ((size_t)bh*NN + n)*WW;
    if (e==0){
        #pragma unroll
        for (int w=0;w<17;w++) pp[w] = sc[w];
    } else {
        #pragma unroll
        for (int w=17;w<WW;w++) pp[w] = sc[w];
    }

    // PV over own half of D
    float acc[16];
    #pragma unroll
    for (int k=0;k<16;k++) acc[k]=0.f;
    #pragma unroll
    for (int w=0;w<WW;w++){
        const float* vr = &Vl[(p+w)*33 + e*16];
        float pw = sc[w];
        #pragma unroll
        for (int k=0;k<16;k++) acc[k] = fmaf(pw, vr[k], acc[k]);
    }

    unsigned short hi[16], lo2[16];
    #pragma unroll
    for (int k=0;k<16;k++){ hi[k]=f2bf(acc[k]); lo2[k]=f2bf(acc[k]-bf2f(hi[k])); }
    size_t aoff = (rowbase + n)*EE + h*DD + e*16;
    #pragma unroll
    for (int k8=0;k8<4;k8++){
        *(ushort4*)(ah + aoff + k8*4) = make_ushort4(hi[k8*4],hi[k8*4+1],hi[k8*4+2],hi[k8*4+3]);
        *(ushort4*)(al + aoff + k8*4) = make_ushort4(lo2[k8*4],lo2[k8*4+1],lo2[k8*4+2],lo2[k8*4+3]);
    }
}

extern "C" void kernel_launch(void* const* d_in, const int* in_sizes, int n_in,
                              void* d_out, int out_size, void* d_ws, size_t ws_size,
                              hipStream_t stream) {
    const float* q  = (const float*)d_in[0];
    const float* Wq = (const float*)d_in[1];  const float* bq = (const float*)d_in[2];
    const float* Wk = (const float*)d_in[3];  const float* bk = (const float*)d_in[4];
    const float* Wv = (const float*)d_in[5];  const float* bv = (const float*)d_in[6];
    const float* Wo = (const float*)d_in[7];  const float* bo = (const float*)d_in[8];

    float* out   = (float*)d_out;             // (B,N,E) = 4194304 floats
    float* probs = out + QELEMS;              // (B,H,N,W) = 4325376 floats

    // workspace carve (~67 MB)
    unsigned short* a_hi = (unsigned short*)d_ws;
    unsigned short* a_lo = a_hi + QELEMS;
    unsigned short* w_hi = a_lo + QELEMS;
    unsigned short* w_lo = w_hi + 4*WELEMS;
    float* Qf = (float*)(w_lo + 4*WELEMS);
    float* Kf = Qf + QELEMS;
    float* Vf = Kf + QELEMS;

    prep_w<<<4*WELEMS/256, 256, 0, stream>>>(Wq, Wk, Wv, Wo, w_hi, w_lo);
    gemm_qkv<<<dim3(MROWS/64, 1), 256, 0, stream>>>(q, w_hi, w_lo,
                                                    bq, bk, bv, Qf, Kf, Vf);
    attn_kernel<<<dim3(NN/128, BN*HH), 256, 0, stream>>>(Qf, Kf, Vf, probs, a_hi, a_lo);
    gemm_o<<<dim3(MROWS/64, 1), 256, 0, stream>>>(a_hi, a_lo,
                                                  w_hi + 3*WELEMS, w_lo + 3*WELEMS, bo, out);
}